// Round 1
// baseline (269.690 us; speedup 1.0000x reference)
//
#include <hip/hip_runtime.h>
#include <math.h>

// Problem constants (from reference)
#define F_   256
#define FEAT_EMB_ 63
#define HID_ 128
#define OUT_ 7

// ---------------------------------------------------------------------------
// 1. Column statistics of x [N, 256]: per-column sum and sum-of-squares
// ---------------------------------------------------------------------------
__global__ __launch_bounds__(256) void colstats_kernel(const float* __restrict__ x,
                                                       float* __restrict__ colsum,
                                                       float* __restrict__ colsq,
                                                       int n, int rows_per_block) {
    int t = threadIdx.x;                 // column
    int r0 = blockIdx.x * rows_per_block;
    int r1 = min(r0 + rows_per_block, n);
    float s = 0.f, sq = 0.f;
    for (int r = r0; r < r1; r++) {
        float v = x[r * F_ + t];
        s += v;
        sq += v * v;
    }
    atomicAdd(&colsum[t], s);
    atomicAdd(&colsq[t], sq);
}

// ---------------------------------------------------------------------------
// 2. Finalize mean / reciprocal-std (population std; std==0 -> 1)
// ---------------------------------------------------------------------------
__global__ void stats_finalize_kernel(const float* __restrict__ colsum,
                                      const float* __restrict__ colsq,
                                      float* __restrict__ mean,
                                      float* __restrict__ rstd, int n) {
    int t = threadIdx.x;
    float m = colsum[t] / (float)n;
    float var = colsq[t] / (float)n - m * m;
    var = fmaxf(var, 0.f);
    float sd = sqrtf(var);
    mean[t] = m;
    rstd[t] = (sd == 0.f) ? 1.f : (1.f / sd);
}

// ---------------------------------------------------------------------------
// 3. In-degree histogram over edges (dst side)
// ---------------------------------------------------------------------------
__global__ void deg_kernel(const int* __restrict__ ei, int* __restrict__ deg, int E) {
    int e = blockIdx.x * 256 + threadIdx.x;
    if (e < E) atomicAdd(&deg[ei[E + e]], 1);
}

// ---------------------------------------------------------------------------
// 4. dinv[n] = rsqrt(deg_edges[n] + 1)   (self loop adds 1; always > 0)
// ---------------------------------------------------------------------------
__global__ void dinv_kernel(const int* __restrict__ deg, float* __restrict__ dinv, int n) {
    int i = blockIdx.x * 256 + threadIdx.x;
    if (i < n) dinv[i] = rsqrtf((float)deg[i] + 1.0f);
}

// ---------------------------------------------------------------------------
// 5. Exclusive scan of deg -> offsets[N+1]  (single block, 1024 threads)
// ---------------------------------------------------------------------------
__global__ __launch_bounds__(1024) void scan_kernel(const int* __restrict__ deg,
                                                    int* __restrict__ offsets, int n) {
    __shared__ int part[1024];
    int t = threadIdx.x;
    int ch = (n + 1023) / 1024;
    int lo = t * ch, hi = min(lo + ch, n);
    int s = 0;
    for (int i = lo; i < hi; i++) s += deg[i];
    part[t] = s;
    __syncthreads();
    // Hillis-Steele inclusive scan
    for (int off = 1; off < 1024; off <<= 1) {
        int v = (t >= off) ? part[t - off] : 0;
        __syncthreads();
        part[t] += v;
        __syncthreads();
    }
    int run = part[t] - s;   // exclusive prefix for this chunk
    if (t == 0) offsets[0] = 0;
    for (int i = lo; i < hi; i++) {
        run += deg[i];
        offsets[i + 1] = run;
    }
}

// ---------------------------------------------------------------------------
// 6. Scatter edges into CSR adjacency (grouped by dst, order arbitrary)
// ---------------------------------------------------------------------------
__global__ void scatter_kernel(const int* __restrict__ ei, const int* __restrict__ offsets,
                               int* __restrict__ cursor, int* __restrict__ adj, int E) {
    int e = blockIdx.x * 256 + threadIdx.x;
    if (e < E) {
        int s = ei[e];
        int d = ei[E + e];
        int pos = offsets[d] + atomicAdd(&cursor[d], 1);
        adj[pos] = s;
    }
}

// ---------------------------------------------------------------------------
// 7. C[k] = sum_{f, j<63} emb[f,j] * W1[f*64+j, k]   (node-independent part)
//    grid 64 blocks x 128 threads, block handles 4 values of f
// ---------------------------------------------------------------------------
__global__ __launch_bounds__(128) void cvec_kernel(const float* __restrict__ emb,
                                                   const float* __restrict__ W1,
                                                   float* __restrict__ Cv) {
    int k = threadIdx.x;
    float s = 0.f;
    int f0 = blockIdx.x * 4;
    for (int f = f0; f < f0 + 4; f++) {
        for (int j = 0; j < FEAT_EMB_; j++) {
            s += emb[f * FEAT_EMB_ + j] * W1[(f * 64 + j) * HID_ + k];
        }
    }
    atomicAdd(&Cv[k], s);
}

// ---------------------------------------------------------------------------
// 8. g0 = (C + xs @ Wv) * dinv    where xs = (x - mean)*rstd, Wv[f,:] = W1 row f*64+63
//    Tiled fp32 GEMM: 32-row tile, full 128 cols, K=256 in 64-chunks.
// ---------------------------------------------------------------------------
__global__ __launch_bounds__(256) void mm1_kernel(const float* __restrict__ x,
                                                  const float* __restrict__ W1,
                                                  const float* __restrict__ mean,
                                                  const float* __restrict__ rstd,
                                                  const float* __restrict__ Cv,
                                                  const float* __restrict__ dinv,
                                                  float* __restrict__ g0, int n) {
    __shared__ float xs[32][64];     // 8 KB
    __shared__ float wt[64][128];    // 32 KB
    int t = threadIdx.x;
    int tx = t & 31;                 // col group: cols tx*4 .. tx*4+3
    int ty = t >> 5;                 // row group: rows ty*4 .. ty*4+3
    int rowBase = blockIdx.x * 32;

    float acc[4][4] = {};

    for (int kb = 0; kb < 256; kb += 64) {
        // stage xs tile: 32 rows x 64 k  (512 float4, 2 per thread)
#pragma unroll
        for (int i = 0; i < 2; i++) {
            int idx = t + i * 256;
            int r = idx >> 4;
            int c4 = (idx & 15) * 4;
            int gr = rowBase + r;
            float4 v;
            if (gr < n) {
                v = *(const float4*)(x + gr * F_ + kb + c4);
                float4 m = *(const float4*)(mean + kb + c4);
                float4 s = *(const float4*)(rstd + kb + c4);
                v.x = (v.x - m.x) * s.x;
                v.y = (v.y - m.y) * s.y;
                v.z = (v.z - m.z) * s.z;
                v.w = (v.w - m.w) * s.w;
            } else {
                v = make_float4(0.f, 0.f, 0.f, 0.f);
            }
            *(float4*)(&xs[r][c4]) = v;
        }
        // stage W tile: 64 k-rows x 128 cols (2048 float4, 8 per thread)
#pragma unroll
        for (int i = 0; i < 8; i++) {
            int idx = t + i * 256;
            int kr = idx >> 5;
            int c4 = (idx & 31) * 4;
            float4 v = *(const float4*)(W1 + ((size_t)((kb + kr) * 64 + 63)) * HID_ + c4);
            *(float4*)(&wt[kr][c4]) = v;
        }
        __syncthreads();

#pragma unroll 4
        for (int k = 0; k < 64; k += 4) {
            float4 wv0 = *(const float4*)(&wt[k + 0][tx * 4]);
            float4 wv1 = *(const float4*)(&wt[k + 1][tx * 4]);
            float4 wv2 = *(const float4*)(&wt[k + 2][tx * 4]);
            float4 wv3 = *(const float4*)(&wt[k + 3][tx * 4]);
#pragma unroll
            for (int i = 0; i < 4; i++) {
                float4 xv = *(const float4*)(&xs[ty * 4 + i][k]);
                acc[i][0] += xv.x * wv0.x; acc[i][1] += xv.x * wv0.y;
                acc[i][2] += xv.x * wv0.z; acc[i][3] += xv.x * wv0.w;
                acc[i][0] += xv.y * wv1.x; acc[i][1] += xv.y * wv1.y;
                acc[i][2] += xv.y * wv1.z; acc[i][3] += xv.y * wv1.w;
                acc[i][0] += xv.z * wv2.x; acc[i][1] += xv.z * wv2.y;
                acc[i][2] += xv.z * wv2.z; acc[i][3] += xv.z * wv2.w;
                acc[i][0] += xv.w * wv3.x; acc[i][1] += xv.w * wv3.y;
                acc[i][2] += xv.w * wv3.z; acc[i][3] += xv.w * wv3.w;
            }
        }
        __syncthreads();
    }

    int cb = tx * 4;
    float4 cv = *(const float4*)(Cv + cb);
#pragma unroll
    for (int i = 0; i < 4; i++) {
        int gr = rowBase + ty * 4 + i;
        if (gr < n) {
            float dv = dinv[gr];
            float4 o;
            o.x = (acc[i][0] + cv.x) * dv;
            o.y = (acc[i][1] + cv.y) * dv;
            o.z = (acc[i][2] + cv.z) * dv;
            o.w = (acc[i][3] + cv.w) * dv;
            *(float4*)(g0 + (size_t)gr * HID_ + cb) = o;
        }
    }
}

// ---------------------------------------------------------------------------
// 9. Layer-1 aggregation + ReLU + fused FC2:
//    one wave per node; lane holds 2 of 128 channels.
//    h[d] = relu(dinv[d]*(g0[d] + sum_in g0[src]) + b1)
//    g2[d][c] = dinv[d] * (h[d] . W2[:,c])   stored padded to stride 8
// ---------------------------------------------------------------------------
__global__ __launch_bounds__(256) void agg_fc2_kernel(const float* __restrict__ g0,
                                                      const int* __restrict__ offsets,
                                                      const int* __restrict__ adj,
                                                      const float* __restrict__ dinv,
                                                      const float* __restrict__ b1,
                                                      const float* __restrict__ W2,
                                                      float* __restrict__ g2, int n) {
    int wave = threadIdx.x >> 6;
    int lane = threadIdx.x & 63;
    int d = blockIdx.x * 4 + wave;
    if (d >= n) return;

    int o0 = offsets[d];
    int o1 = offsets[d + 1];
    float2 acc = *(const float2*)(g0 + (size_t)d * HID_ + lane * 2);  // self loop
    for (int i = o0; i < o1; i++) {
        int s = adj[i];
        float2 v = *(const float2*)(g0 + (size_t)s * HID_ + lane * 2);
        acc.x += v.x;
        acc.y += v.y;
    }
    float dv = dinv[d];
    float2 bb = *(const float2*)(b1 + lane * 2);
    float h0 = fmaxf(acc.x * dv + bb.x, 0.f);
    float h1 = fmaxf(acc.y * dv + bb.y, 0.f);

    // FC2: 7 wave-reductions (all lanes end up with the total)
    const float* w2a = W2 + (lane * 2) * OUT_;
    const float* w2b = W2 + (lane * 2 + 1) * OUT_;
    float r[OUT_];
#pragma unroll
    for (int c = 0; c < OUT_; c++) {
        float p = h0 * w2a[c] + h1 * w2b[c];
#pragma unroll
        for (int off = 32; off > 0; off >>= 1) p += __shfl_xor(p, off);
        r[c] = p;
    }
    if (lane < 8) {
        float val;
        switch (lane) {
            case 0: val = r[0]; break;
            case 1: val = r[1]; break;
            case 2: val = r[2]; break;
            case 3: val = r[3]; break;
            case 4: val = r[4]; break;
            case 5: val = r[5]; break;
            case 6: val = r[6]; break;
            default: val = 0.f; break;   // pad slot
        }
        g2[(size_t)d * 8 + lane] = val * dv;
    }
}

// ---------------------------------------------------------------------------
// 10. Layer-2 aggregation + bias + log_softmax. 8 lanes per node (7 classes + pad).
// ---------------------------------------------------------------------------
__global__ __launch_bounds__(256) void agg2_softmax_kernel(const float* __restrict__ g2,
                                                           const int* __restrict__ offsets,
                                                           const int* __restrict__ adj,
                                                           const float* __restrict__ dinv,
                                                           const float* __restrict__ b2,
                                                           float* __restrict__ out, int n) {
    int t = threadIdx.x;
    int g = t >> 3;      // node within block (0..31)
    int c = t & 7;       // class lane (7 == pad)
    int d = blockIdx.x * 32 + g;
    if (d >= n) return;

    int o0 = offsets[d];
    int o1 = offsets[d + 1];
    float acc = g2[(size_t)d * 8 + c];       // self loop (pad slot holds 0)
    for (int i = o0; i < o1; i++) {
        int s = adj[i];
        acc += g2[(size_t)s * 8 + c];
    }
    float z = (c < OUT_) ? (acc * dinv[d] + b2[c]) : -INFINITY;
    float m = z;
#pragma unroll
    for (int off = 4; off > 0; off >>= 1) m = fmaxf(m, __shfl_xor(m, off, 8));
    float e = (c < OUT_) ? __expf(z - m) : 0.f;
    float sum = e;
#pragma unroll
    for (int off = 4; off > 0; off >>= 1) sum += __shfl_xor(sum, off, 8);
    if (c < OUT_) out[(size_t)d * OUT_ + c] = z - m - __logf(sum);
}

// ---------------------------------------------------------------------------
// launch
// ---------------------------------------------------------------------------
extern "C" void kernel_launch(void* const* d_in, const int* in_sizes, int n_in,
                              void* d_out, int out_size, void* d_ws, size_t ws_size,
                              hipStream_t stream) {
    const float* x    = (const float*)d_in[0];
    const float* emb  = (const float*)d_in[1];
    const float* W1   = (const float*)d_in[2];
    const float* b1   = (const float*)d_in[3];
    const float* W2   = (const float*)d_in[4];
    const float* b2   = (const float*)d_in[5];
    const int*   ei   = (const int*)d_in[6];
    float* out = (float*)d_out;

    const int N = in_sizes[0] / F_;       // 20000
    const int E = in_sizes[6] / 2;        // 320000

    // workspace layout (element offsets, all 4-byte elems)
    float* ws = (float*)d_ws;
    size_t o = 0;
    float* colsum  = ws + o; o += F_;          // 256
    float* colsq   = ws + o; o += F_;          // 256
    float* mean    = ws + o; o += F_;
    float* rstd    = ws + o; o += F_;
    float* Cv      = ws + o; o += HID_;        // 128
    size_t zero1_elems = o;                    // zero everything up to here
    float* dinv    = ws + o; o += N;
    int*   deg     = (int*)(ws + o); o += N;
    int*   cursor  = (int*)(ws + o); o += N;   // contiguous with deg -> one memset
    int*   offsets = (int*)(ws + o); o += (size_t)N + 1;
    o = (o + 3) & ~(size_t)3;                  // align
    int*   adj     = (int*)(ws + o); o += E;
    o = (o + 3) & ~(size_t)3;
    float* g0      = ws + o; o += (size_t)N * HID_;
    float* g2      = ws + o; o += (size_t)N * 8;

    // zero accumulators (re-poisoned to 0xAA before every launch)
    hipMemsetAsync(ws, 0, zero1_elems * sizeof(float), stream);
    hipMemsetAsync(deg, 0, (size_t)2 * N * sizeof(int), stream);

    // column stats
    {
        int blocks = 200;
        int rpb = (N + blocks - 1) / blocks;
        colstats_kernel<<<blocks, 256, 0, stream>>>(x, colsum, colsq, N, rpb);
    }
    // degree histogram
    deg_kernel<<<(E + 255) / 256, 256, 0, stream>>>(ei, deg, E);
    // finalize stats
    stats_finalize_kernel<<<1, 256, 0, stream>>>(colsum, colsq, mean, rstd, N);
    // dinv
    dinv_kernel<<<(N + 255) / 256, 256, 0, stream>>>(deg, dinv, N);
    // CSR offsets
    scan_kernel<<<1, 1024, 0, stream>>>(deg, offsets, N);
    // CSR adjacency
    scatter_kernel<<<(E + 255) / 256, 256, 0, stream>>>(ei, offsets, cursor, adj, E);
    // constant vector C
    cvec_kernel<<<64, 128, 0, stream>>>(emb, W1, Cv);
    // g0 = (C + xs @ Wv) * dinv
    mm1_kernel<<<(N + 31) / 32, 256, 0, stream>>>(x, W1, mean, rstd, Cv, dinv, g0, N);
    // layer-1 aggregation + relu + FC2
    agg_fc2_kernel<<<(N + 3) / 4, 256, 0, stream>>>(g0, offsets, adj, dinv, b1, W2, g2, N);
    // layer-2 aggregation + log_softmax
    agg2_softmax_kernel<<<(N + 31) / 32, 256, 0, stream>>>(g2, offsets, adj, dinv, b2, out, N);
}